// Round 12
// baseline (87.146 us; speedup 1.0000x reference)
//
#include <hip/hip_runtime.h>
#include <math.h>
#include <limits.h>

#define NUM_CODES 1024
#define DIM 64
#define HW 1024
#define NPTS 65536
#define PTS 32             // points per block
#define CAP 16
#define W_WINDOW 6.0e-4f   // >= 2*Delta_hh (4.8e-4 worst-case); lambda~0.4

using short8 = __attribute__((ext_vector_type(8))) short;
using f32x4  = __attribute__((ext_vector_type(4))) float;

// ---- numpy-exact helpers (verified rounds 2-11: absmax 0.0) ----
__device__ __forceinline__ float pairwise_sumsq64(const float* v) {
    float r[8];
#pragma unroll
    for (int j = 0; j < 8; ++j) r[j] = __fmul_rn(v[j], v[j]);
#pragma unroll
    for (int i = 8; i < 64; i += 8) {
#pragma unroll
        for (int j = 0; j < 8; ++j)
            r[j] = __fadd_rn(r[j], __fmul_rn(v[i + j], v[i + j]));
    }
    return __fadd_rn(
        __fadd_rn(__fadd_rn(r[0], r[1]), __fadd_rn(r[2], r[3])),
        __fadd_rn(__fadd_rn(r[4], r[5]), __fadd_rn(r[6], r[7])));
}

__device__ __forceinline__ float replica_d(const float* x, const float* wr,
                                           float t1, float t3k) {
    float acc = 0.0f;
#pragma unroll
    for (int j = 0; j < 64; ++j) acc = __fmaf_rn(x[j], wr[j], acc);
    return __fadd_rn(__fsub_rn(t1, __fmul_rn(2.0f, acc)), t3k);
}

__device__ __forceinline__ unsigned short bf16_rne(float v) {
    unsigned int u = __float_as_uint(v);
    return (unsigned short)((u + 0x7fffu + ((u >> 16) & 1u)) >> 16);
}

// ---- Kernel 0: prep  wneg2hi = bf16(-2*w)  + t3 (numpy-exact) ----
__global__ void vq_prep_kernel(const float* __restrict__ w,
                               unsigned short* __restrict__ wneg2hi,
                               float* __restrict__ t3) {
    int k = blockIdx.x * blockDim.x + threadIdx.x;
    if (k >= NUM_CODES) return;
    float row[64];
#pragma unroll
    for (int j = 0; j < 64; ++j) row[j] = w[k * DIM + j];
    t3[k] = pairwise_sumsq64(row);
#pragma unroll
    for (int j = 0; j < 64; ++j) wneg2hi[k * DIM + j] = bf16_rne(-2.0f * row[j]);
}

// ---- Kernel 1: main. Block = 256 thr = 4 waves; 32 points (2 point-tiles).
// Code-split: wave wv handles BOTH point-tiles x codes [wv*256, wv*256+256).
// C-init trick (r11): acc starts at t3[code], B pre-scaled by -2 -> s = c[r].
// Selection: 8 threads per point, lexicographic (d,k) shfl reduce.
__global__ __launch_bounds__(256, 2) void vq_main_kernel(
        const float* __restrict__ z,
        const float* __restrict__ w,
        const unsigned short* __restrict__ wneg2hi,
        const float* __restrict__ t3,
        float* __restrict__ out) {
    __shared__ __align__(16) unsigned short s_xhi[PTS * 72];
    __shared__ float s_pmin[4][PTS];
    __shared__ float s_thr[PTS];
    __shared__ int s_list[PTS * CAP];
    __shared__ int s_cnt[PTS];
    __shared__ int s_best[PTS];

    const int tid = threadIdx.x;
    const int lane = tid & 63;
    const int wv = tid >> 6;          // 0..3
    const int n0 = blockIdx.x * PTS;
    const int b = n0 >> 10;
    const int hw0 = n0 & (HW - 1);

    if (tid < PTS) s_cnt[tid] = 0;

    // stage 32 points as bf16-hi into LDS; coalesced 32-wide global reads
    {
        int hw_off = tid & 31;
        int dbase = tid >> 5;         // 0..7
#pragma unroll
        for (int i = 0; i < 8; ++i) {
            int d = dbase + i * 8;
            float v = z[((size_t)(b * 64 + d)) * HW + hw0 + hw_off];
            s_xhi[hw_off * 72 + d] = bf16_rne(v);
        }
    }
    __syncthreads();

    const int col = lane & 15;
    const int q = lane >> 4;

    // A fragments for both point-tiles (hi only; layout verified r3-r11)
    short8 ah0[2], ah1[2];
#pragma unroll
    for (int at = 0; at < 2; ++at) {
        int arow = at * 16 + col;
        ah0[at] = *(const short8*)&s_xhi[arow * 72 + q * 8];
        ah1[at] = *(const short8*)&s_xhi[arow * 72 + 32 + q * 8];
    }

    const int T0 = wv * 16;

    // ---- pass 1: per-point min over this wave's 256 codes ----
    float s1[2][4];
#pragma unroll
    for (int at = 0; at < 2; ++at)
#pragma unroll
        for (int r = 0; r < 4; ++r) s1[at][r] = INFINITY;

#pragma unroll 4
    for (int t = 0; t < 16; ++t) {
        int code = (T0 + t) * 16 + col;
        short8 b0 = *(const short8*)(wneg2hi + code * 64 + q * 8);
        short8 b1 = *(const short8*)(wneg2hi + code * 64 + 32 + q * 8);
        float t3v = t3[code];
        f32x4 cinit = {t3v, t3v, t3v, t3v};
#pragma unroll
        for (int at = 0; at < 2; ++at) {
            f32x4 c = cinit;
            c = __builtin_amdgcn_mfma_f32_16x16x32_bf16(ah0[at], b0, c, 0, 0, 0);
            c = __builtin_amdgcn_mfma_f32_16x16x32_bf16(ah1[at], b1, c, 0, 0, 0);
#pragma unroll
            for (int r = 0; r < 4; ++r)
                s1[at][r] = fminf(s1[at][r], c[r]);
        }
    }

    // reduce over the 16 lanes (col bits) sharing each point
#pragma unroll
    for (int mask = 1; mask <= 8; mask <<= 1)
#pragma unroll
        for (int at = 0; at < 2; ++at)
#pragma unroll
            for (int r = 0; r < 4; ++r)
                s1[at][r] = fminf(s1[at][r], __shfl_xor(s1[at][r], mask, 64));

    if (col == 0) {
#pragma unroll
        for (int at = 0; at < 2; ++at)
#pragma unroll
            for (int r = 0; r < 4; ++r)
                s_pmin[wv][at * 16 + q * 4 + r] = s1[at][r];
    }
    __syncthreads();

    if (tid < PTS) {
        float m = fminf(fminf(s_pmin[0][tid], s_pmin[1][tid]),
                        fminf(s_pmin[2][tid], s_pmin[3][tid]));
        s_thr[tid] = m + W_WINDOW;
    }
    __syncthreads();

    float thr[2][4];
#pragma unroll
    for (int at = 0; at < 2; ++at)
#pragma unroll
        for (int r = 0; r < 4; ++r)
            thr[at][r] = s_thr[at * 16 + q * 4 + r];

    // ---- pass 2: recompute scores (bitwise-identical), collect candidates ----
#pragma unroll 4
    for (int t = 0; t < 16; ++t) {
        int code = (T0 + t) * 16 + col;
        short8 b0 = *(const short8*)(wneg2hi + code * 64 + q * 8);
        short8 b1 = *(const short8*)(wneg2hi + code * 64 + 32 + q * 8);
        float t3v = t3[code];
        f32x4 cinit = {t3v, t3v, t3v, t3v};
#pragma unroll
        for (int at = 0; at < 2; ++at) {
            f32x4 c = cinit;
            c = __builtin_amdgcn_mfma_f32_16x16x32_bf16(ah0[at], b0, c, 0, 0, 0);
            c = __builtin_amdgcn_mfma_f32_16x16x32_bf16(ah1[at], b1, c, 0, 0, 0);
#pragma unroll
            for (int r = 0; r < 4; ++r) {
                if (c[r] <= thr[at][r]) {
                    int pt = at * 16 + q * 4 + r;
                    int idx = atomicAdd(&s_cnt[pt], 1);
                    if (idx < CAP) s_list[pt * CAP + idx] = code;
                }
            }
        }
    }
    __syncthreads();

    // ---- selection: 8 threads per point; exact fp32 replica; lex (d,k) min ----
    {
        int pt = tid >> 3;            // 0..31
        int sl = tid & 7;             // 0..7 (contiguous lanes, same wave)
        int m = s_cnt[pt];
        int best;
        if (m <= 1) {
            best = s_list[pt * CAP];  // min always collected -> m >= 1
        } else {
            float x[64];
#pragma unroll
            for (int j = 0; j < 64; ++j)
                x[j] = z[((size_t)(b * 64 + j)) * HW + hw0 + pt];
            float t1 = pairwise_sumsq64(x);
            float dbest = INFINITY;
            int kbest = INT_MAX;
            if (m <= CAP) {
                for (int i = sl; i < m; i += 8) {
                    int k = s_list[pt * CAP + i];
                    float d = replica_d(x, w + (size_t)k * DIM, t1, t3[k]);
                    if (d < dbest || (d == dbest && k < kbest)) { dbest = d; kbest = k; }
                }
            } else {
                // overflow guard (P ~ 0): distributed exact scan
                for (int k = sl; k < NUM_CODES; k += 8) {
                    float d = replica_d(x, w + (size_t)k * DIM, t1, t3[k]);
                    if (d < dbest || (d == dbest && k < kbest)) { dbest = d; kbest = k; }
                }
            }
            // 8-lane lexicographic (d, k) min == first-occurrence argmin
#pragma unroll
            for (int mask = 1; mask <= 4; mask <<= 1) {
                float od = __shfl_xor(dbest, mask, 64);
                int ok = __shfl_xor(kbest, mask, 64);
                if (od < dbest || (od == dbest && ok < kbest)) { dbest = od; kbest = ok; }
            }
            best = kbest;
        }
        if (sl == 0) s_best[pt] = best;
    }
    __syncthreads();

    // ---- output: out[b, c, hw0+pt] = w[best[pt]][c], coalesced 32-wide ----
    {
        int pt = tid & 31;
        int cb = tid >> 5;            // 0..7
        int bk = s_best[pt];
        const float* wrow = w + (size_t)bk * DIM;
#pragma unroll
        for (int i = 0; i < 8; ++i) {
            int c = cb + i * 8;
            out[((size_t)(b * 64 + c)) * HW + hw0 + pt] = wrow[c];
        }
    }
}

extern "C" void kernel_launch(void* const* d_in, const int* in_sizes, int n_in,
                              void* d_out, int out_size, void* d_ws, size_t ws_size,
                              hipStream_t stream) {
    const float* z = (const float*)d_in[0];
    const float* w = (const float*)d_in[1];
    float* out = (float*)d_out;

    unsigned short* wneg2hi = (unsigned short*)d_ws;    // 128 KB
    float* t3 = (float*)((char*)d_ws + 131072);         // 4 KB

    vq_prep_kernel<<<NUM_CODES / 256, 256, 0, stream>>>(w, wneg2hi, t3);
    vq_main_kernel<<<NPTS / PTS, 256, 0, stream>>>(z, w, wneg2hi, t3, out);
}

// Round 13
// 78.097 us; speedup vs baseline: 1.1159x; 1.1159x over previous
//
#include <hip/hip_runtime.h>
#include <math.h>
#include <limits.h>

#define NUM_CODES 1024
#define DIM 64
#define HW 1024
#define NPTS 65536
#define PTS 64             // points per block
#define CAP 32
#define W_WINDOW 6.0e-4f   // >= 2*Delta_hh (4.8e-4 worst-case); validated r10-12

using short8 = __attribute__((ext_vector_type(8))) short;
using f32x4  = __attribute__((ext_vector_type(4))) float;

// ---- numpy-exact helpers (verified rounds 2-12: absmax 0.0) ----
__device__ __forceinline__ float pairwise_sumsq64(const float* v) {
    float r[8];
#pragma unroll
    for (int j = 0; j < 8; ++j) r[j] = __fmul_rn(v[j], v[j]);
#pragma unroll
    for (int i = 8; i < 64; i += 8) {
#pragma unroll
        for (int j = 0; j < 8; ++j)
            r[j] = __fadd_rn(r[j], __fmul_rn(v[i + j], v[i + j]));
    }
    return __fadd_rn(
        __fadd_rn(__fadd_rn(r[0], r[1]), __fadd_rn(r[2], r[3])),
        __fadd_rn(__fadd_rn(r[4], r[5]), __fadd_rn(r[6], r[7])));
}

__device__ __forceinline__ float replica_d(const float* x, const float* wr,
                                           float t1, float t3k) {
    float acc = 0.0f;
#pragma unroll
    for (int j = 0; j < 64; ++j) acc = __fmaf_rn(x[j], wr[j], acc);
    return __fadd_rn(__fsub_rn(t1, __fmul_rn(2.0f, acc)), t3k);
}

__device__ __forceinline__ unsigned short bf16_rne(float v) {
    unsigned int u = __float_as_uint(v);
    return (unsigned short)((u + 0x7fffu + ((u >> 16) & 1u)) >> 16);
}

// monotone float<->uint order map (total order, handles negatives)
__device__ __forceinline__ unsigned int fenc(float f) {
    unsigned int u = __float_as_uint(f);
    return (u & 0x80000000u) ? ~u : (u | 0x80000000u);
}
__device__ __forceinline__ float fdec(unsigned int u) {
    return __uint_as_float((u & 0x80000000u) ? (u ^ 0x80000000u) : ~u);
}

// ---- Kernel 0: prep  wneg2hi = bf16(-2*w)  + t3 (numpy-exact) ----
__global__ void vq_prep_kernel(const float* __restrict__ w,
                               unsigned short* __restrict__ wneg2hi,
                               float* __restrict__ t3) {
    int k = blockIdx.x * blockDim.x + threadIdx.x;
    if (k >= NUM_CODES) return;
    float row[64];
#pragma unroll
    for (int j = 0; j < 64; ++j) row[j] = w[k * DIM + j];
    t3[k] = pairwise_sumsq64(row);
#pragma unroll
    for (int j = 0; j < 64; ++j) wneg2hi[k * DIM + j] = bf16_rne(-2.0f * row[j]);
}

// ---- Kernel 1: SINGLE-PASS main. 256 thr = 4 waves; 64 points.
// Operand swap: mfma(A=codes, B=points) -> C: code=(lane>>4)*4+r, point=lane&15.
// Online threshold: LDS atomicMin of encoded min; update-then-insert keeps the
// collected set a superset of {k : s_k <= final_min + W}. Selection filters by
// final min then exact-fp32-replica re-ranks (lex (d,k) = first occurrence).
__global__ __launch_bounds__(256, 2) void vq_main_kernel(
        const float* __restrict__ z,
        const float* __restrict__ w,
        const unsigned short* __restrict__ wneg2hi,
        const float* __restrict__ t3,
        float* __restrict__ out) {
    __shared__ __align__(16) unsigned short s_xhi[PTS * 72];
    __shared__ unsigned int s_minU[PTS];
    __shared__ float s_ls[PTS * CAP];
    __shared__ int s_lk[PTS * CAP];
    __shared__ int s_cnt[PTS];
    __shared__ int s_best[PTS];

    const int tid = threadIdx.x;
    const int lane = tid & 63;
    const int wv = tid >> 6;          // 0..3
    const int n0 = blockIdx.x * PTS;
    const int b = n0 >> 10;
    const int hw0 = n0 & (HW - 1);

    if (tid < PTS) { s_cnt[tid] = 0; s_minU[tid] = fenc(3.0e38f); }

    // stage 64 points as bf16-hi into LDS; coalesced 64-wide global reads
    {
        int hw_off = tid & 63;
        int dbase = tid >> 6;
#pragma unroll
        for (int i = 0; i < 16; ++i) {
            int d = dbase + i * 4;
            float v = z[((size_t)(b * 64 + d)) * HW + hw0 + hw_off];
            s_xhi[hw_off * 72 + d] = bf16_rne(v);
        }
    }
    __syncthreads();

    const int col = lane & 15;
    const int q = lane >> 4;

    // B fragments = the 4 point-tiles (identical construction to r11's A-frags)
    short8 bh0[4], bh1[4];
#pragma unroll
    for (int at = 0; at < 4; ++at) {
        int brow = at * 16 + col;
        bh0[at] = *(const short8*)&s_xhi[brow * 72 + q * 8];
        bh1[at] = *(const short8*)&s_xhi[brow * 72 + 32 + q * 8];
    }

    // per-at running min (for this lane's point at*16+col), in registers
    float thrmin[4];
#pragma unroll
    for (int at = 0; at < 4; ++at) thrmin[at] = 3.0e38f;

    const int T0 = wv * 16;

    // ---- SINGLE PASS: score 256 codes, online-collect candidates ----
#pragma unroll 4
    for (int t = 0; t < 16; ++t) {
        int tbase = (T0 + t) * 16;               // code tile base
        int crow = tbase + col;                  // this lane's A row (code)
        short8 a0 = *(const short8*)(wneg2hi + crow * 64 + q * 8);
        short8 a1 = *(const short8*)(wneg2hi + crow * 64 + 32 + q * 8);
        f32x4 t34 = *(const f32x4*)(t3 + tbase + q * 4);   // t3 for codes q*4+r
#pragma unroll
        for (int at = 0; at < 4; ++at) {
            f32x4 c = t34;
            c = __builtin_amdgcn_mfma_f32_16x16x32_bf16(a0, bh0[at], c, 0, 0, 0);
            c = __builtin_amdgcn_mfma_f32_16x16x32_bf16(a1, bh1[at], c, 0, 0, 0);
            // lane-local min over 4 codes, merge across the 4 q-lanes
            float lmin = fminf(fminf(c[0], c[1]), fminf(c[2], c[3]));
            lmin = fminf(lmin, __shfl_xor(lmin, 16, 64));
            lmin = fminf(lmin, __shfl_xor(lmin, 32, 64));
            int pt = at * 16 + col;
            // merge with cross-wave min (LDS), publish improvement
            float newmin = fminf(thrmin[at], lmin);
            unsigned int sharedU = s_minU[pt];
            float sharedMin = fdec(sharedU);
            if (newmin < sharedMin) {
                atomicMin(&s_minU[pt], fenc(newmin));
            } else {
                newmin = fminf(newmin, sharedMin);
            }
            thrmin[at] = newmin;
            float thrW = newmin + W_WINDOW;
            // insert (update-then-insert: thr >= final_min + W, conservative)
#pragma unroll
            for (int r = 0; r < 4; ++r) {
                if (c[r] <= thrW) {
                    int idx = atomicAdd(&s_cnt[pt], 1);
                    if (idx < CAP) {
                        s_ls[pt * CAP + idx] = c[r];
                        s_lk[pt * CAP + idx] = tbase + q * 4 + r;
                    }
                }
            }
        }
    }
    __syncthreads();

    // ---- selection: 4 threads per point; filter by final min; exact replica ----
    {
        int pt = tid >> 2;            // 0..63
        int sl = tid & 3;             // 0..3
        int cnt = s_cnt[pt];
        int best;
        if (cnt > CAP) {
            // overflow guard (rare): distributed exact scan over all codes
            float x[64];
#pragma unroll
            for (int j = 0; j < 64; ++j)
                x[j] = z[((size_t)(b * 64 + j)) * HW + hw0 + pt];
            float t1 = pairwise_sumsq64(x);
            float dbest = INFINITY;
            int kbest = INT_MAX;
            for (int k = sl; k < NUM_CODES; k += 4) {
                float d = replica_d(x, w + (size_t)k * DIM, t1, t3[k]);
                if (d < dbest || (d == dbest && k < kbest)) { dbest = d; kbest = k; }
            }
#pragma unroll
            for (int mask = 1; mask <= 2; mask <<= 1) {
                float od = __shfl_xor(dbest, mask, 64);
                int ok = __shfl_xor(kbest, mask, 64);
                if (od < dbest || (od == dbest && ok < kbest)) { dbest = od; kbest = ok; }
            }
            best = kbest;
        } else {
            float thrF = fdec(s_minU[pt]) + W_WINDOW;
            // count passing candidates (no x needed yet)
            int myc = 0, mylast = -1;
            for (int i = sl; i < cnt; i += 4) {
                if (s_ls[pt * CAP + i] <= thrF) { ++myc; mylast = s_lk[pt * CAP + i]; }
            }
            int totc = myc;
            int lastk = (myc ? mylast : -1);
#pragma unroll
            for (int mask = 1; mask <= 2; mask <<= 1) {
                totc += __shfl_xor(totc, mask, 64);
                int ok = __shfl_xor(lastk, mask, 64);
                lastk = max(lastk, ok);
            }
            if (totc <= 1) {
                best = lastk;          // exactly the window min (always collected)
            } else {
                float x[64];
#pragma unroll
                for (int j = 0; j < 64; ++j)
                    x[j] = z[((size_t)(b * 64 + j)) * HW + hw0 + pt];
                float t1 = pairwise_sumsq64(x);
                float dbest = INFINITY;
                int kbest = INT_MAX;
                for (int i = sl; i < cnt; i += 4) {
                    if (s_ls[pt * CAP + i] <= thrF) {
                        int k = s_lk[pt * CAP + i];
                        float d = replica_d(x, w + (size_t)k * DIM, t1, t3[k]);
                        if (d < dbest || (d == dbest && k < kbest)) { dbest = d; kbest = k; }
                    }
                }
#pragma unroll
                for (int mask = 1; mask <= 2; mask <<= 1) {
                    float od = __shfl_xor(dbest, mask, 64);
                    int ok = __shfl_xor(kbest, mask, 64);
                    if (od < dbest || (od == dbest && ok < kbest)) { dbest = od; kbest = ok; }
                }
                best = kbest;
            }
        }
        if (sl == 0) s_best[pt] = best;
    }
    __syncthreads();

    // ---- output: out[b, c, hw0+pt] = w[best[pt]][c], coalesced 64-wide ----
    {
        int pt = tid & 63;
        int cb = tid >> 6;            // 0..3
        int bk = s_best[pt];
        const float* wrow = w + (size_t)bk * DIM;
#pragma unroll
        for (int i = 0; i < 16; ++i) {
            int c = cb + i * 4;
            out[((size_t)(b * 64 + c)) * HW + hw0 + pt] = wrow[c];
        }
    }
}

extern "C" void kernel_launch(void* const* d_in, const int* in_sizes, int n_in,
                              void* d_out, int out_size, void* d_ws, size_t ws_size,
                              hipStream_t stream) {
    const float* z = (const float*)d_in[0];
    const float* w = (const float*)d_in[1];
    float* out = (float*)d_out;

    unsigned short* wneg2hi = (unsigned short*)d_ws;    // 128 KB
    float* t3 = (float*)((char*)d_ws + 131072);         // 4 KB

    vq_prep_kernel<<<NUM_CODES / 256, 256, 0, stream>>>(w, wneg2hi, t3);
    vq_main_kernel<<<NPTS / PTS, 256, 0, stream>>>(z, w, wneg2hi, t3, out);
}